// Round 5
// baseline (201.550 us; speedup 1.0000x reference)
//
#include <hip/hip_runtime.h>
#include <hip/hip_bf16.h>
#include <math.h>

// B=8, H=W=128, CH=64, OC=64, NCA_C=128, K=3, dils {1,2,4,8}, HID=64
// out: y [8,128,128,64] fp32 (8388608) then c2 [8,64] fp32 (512)
//
// Depthwise conv folded into GEMM1: hidden[p] = sum_{37 pos} xpad[p+delta,0:64] @ U_pos.
// Round-5 change: U (B-operand) staged in LDS, double-buffered in 4-position chunks
// (cuts the 4x per-wave B redundancy -> global L2 traffic 1.21 GB -> 0.75 GB; B reads
// move to the LDS pipe). A stays register-double-buffered from zero-padded bf16 image.
// b = blk&7 -> XCD-local L2 (FETCH ~12 MB, verified round 3/4).

typedef float  f32x4 __attribute__((ext_vector_type(4)));
typedef short  s16x8 __attribute__((ext_vector_type(8)));

static __device__ __forceinline__ unsigned short f2bf(float f) {
    __hip_bfloat16 h = __float2bfloat16(f);
    unsigned short u; __builtin_memcpy(&u, &h, 2); return u;
}

// xpad layout: [b][plane(4)][yy(144)][xx(144)][16ch] bf16
#define XROW   2304
#define XPLANE 331776
#define XBATCH 1327104

// ---------------- prepA: x -> padded bf16, pad zero-fill, c2 ----------------
__global__ void prepA(const float* __restrict__ x, const float* __restrict__ c,
                      const float* __restrict__ Wv, const float* __restrict__ bv,
                      const float* __restrict__ Wo, const float* __restrict__ bo,
                      const float* __restrict__ lng, const float* __restrict__ lnb,
                      unsigned short* __restrict__ xp, float* __restrict__ c2f,
                      float* __restrict__ outc2)
{
    const int blk = blockIdx.x, tid = threadIdx.x;
    if (blk < 512) {
        int i = blk*256 + tid;               // px index [0,131072)
        int xc = i & 127, y = (i >> 7) & 127, b = i >> 14;
        const float* src = x + (size_t)i*64;
        unsigned short* dstb = xp + ((size_t)b*4*144 + (y+8))*XROW + (xc+8)*16;
        #pragma unroll
        for (int p = 0; p < 4; ++p) {
            float4 f0 = *(const float4*)(src + p*16 + 0);
            float4 f1 = *(const float4*)(src + p*16 + 4);
            float4 f2 = *(const float4*)(src + p*16 + 8);
            float4 f3 = *(const float4*)(src + p*16 + 12);
            uint4 o0, o1;
            o0.x = (unsigned)f2bf(f0.x) | ((unsigned)f2bf(f0.y) << 16);
            o0.y = (unsigned)f2bf(f0.z) | ((unsigned)f2bf(f0.w) << 16);
            o0.z = (unsigned)f2bf(f1.x) | ((unsigned)f2bf(f1.y) << 16);
            o0.w = (unsigned)f2bf(f1.z) | ((unsigned)f2bf(f1.w) << 16);
            o1.x = (unsigned)f2bf(f2.x) | ((unsigned)f2bf(f2.y) << 16);
            o1.y = (unsigned)f2bf(f2.z) | ((unsigned)f2bf(f2.w) << 16);
            o1.z = (unsigned)f2bf(f3.x) | ((unsigned)f2bf(f3.y) << 16);
            o1.w = (unsigned)f2bf(f3.z) | ((unsigned)f2bf(f3.w) << 16);
            unsigned short* d = dstb + (size_t)p*XPLANE;
            *(uint4*)d = o0; *(uint4*)(d + 8) = o1;
        }
    } else if (blk < 1056) {
        int idx = (blk - 512)*256 + tid;     // [0,139264) pad px
        int bp = idx / 4352;                 // b*4+plane
        int r  = idx - bp*4352;
        int yy, xx;
        if (r < 2304) { int ry = r / 144; xx = r - ry*144; yy = (ry < 8) ? ry : 128 + ry; }
        else { int r2 = r - 2304; yy = 8 + (r2 >> 4); int xi = r2 & 15; xx = (xi < 8) ? xi : 128 + xi; }
        uint4 z = make_uint4(0,0,0,0);
        unsigned short* d = xp + ((size_t)bp*144 + yy)*XROW + xx*16;
        *(uint4*)d = z; *(uint4*)(d + 8) = z;
    } else {
        // c2 = c + LN(v@Wo + bo + c), v = c@Wv + bv  (softmax pool == v exactly)
        const int b = blk - 1056;
        __shared__ float sc[64], sv[64];
        const int j = tid;
        if (j < 64) sc[j] = c[b*64 + j];
        __syncthreads();
        if (j < 64) {
            float v = bv[j];
            for (int i = 0; i < 64; ++i) v += sc[i]*Wv[i*64 + j];
            sv[j] = v;
        }
        __syncthreads();
        if (j < 64) {
            float t = bo[j] + sc[j];
            for (int i = 0; i < 64; ++i) t += sv[i]*Wo[i*64 + j];
            float s = t;
            for (int o = 32; o > 0; o >>= 1) s += __shfl_xor(s, o);
            float m = s * (1.f/64.f);
            float dq = (t - m)*(t - m);
            for (int o = 32; o > 0; o >>= 1) dq += __shfl_xor(dq, o);
            float a = (t - m) / sqrtf(dq*(1.f/64.f) + 1e-5f) * lng[j] + lnb[j];
            float c2 = sc[j] + a;
            c2f[b*64 + j] = c2;
            outc2[b*64 + j] = c2;
        }
    }
}

// ---------------- prepB: U frags, W2 frags, V vectors, hcpart ---------------
__global__ void prepB(const float* __restrict__ pk, const float* __restrict__ W1,
                      const float* __restrict__ W2, const float* __restrict__ b1,
                      const float* __restrict__ c2f,
                      unsigned short* __restrict__ Uf, unsigned short* __restrict__ W2s,
                      float* __restrict__ V, float* __restrict__ hcp)
{
    const int blk = blockIdx.x, tid = threadIdx.x;
    if (blk < 74) {
        int idx = blk*256 + tid;            // [0, 18944) = 37*512
        int lane = idx & 63, nt = (idx >> 6) & 3, kc2 = (idx >> 8) & 1, pos = idx >> 9;
        int n  = nt*16 + (lane & 15);
        int k0 = kc2*32 + (lane >> 4)*8;
        unsigned short e[8];
        if (pos == 0) {
            #pragma unroll
            for (int j = 0; j < 8; ++j) e[j] = f2bf(W1[(k0+j)*64 + n]);
        } else {
            int di = (pos-1)/9, t = (pos-1)%9;
            #pragma unroll
            for (int j = 0; j < 8; ++j) {
                int ch = k0 + j;
                e[j] = f2bf(pk[(di*128 + ch)*9 + t] * W1[((1+di)*128 + ch)*64 + n]);
            }
        }
        uint4 o;
        o.x = (unsigned)e[0] | ((unsigned)e[1] << 16);
        o.y = (unsigned)e[2] | ((unsigned)e[3] << 16);
        o.z = (unsigned)e[4] | ((unsigned)e[5] << 16);
        o.w = (unsigned)e[6] | ((unsigned)e[7] << 16);
        *(uint4*)(Uf + (size_t)idx*8) = o;
    } else if (blk < 76) {
        int idx = (blk-74)*256 + tid;       // [0,512)
        int lane = idx & 63, nt = (idx >> 6) & 3, kc2 = (idx >> 8) & 1;
        int n  = nt*16 + (lane & 15);
        int k0 = kc2*32 + (lane >> 4)*8;
        unsigned short e[8];
        #pragma unroll
        for (int j = 0; j < 8; ++j) e[j] = f2bf(W2[(k0+j)*64 + n]);
        uint4 o;
        o.x = (unsigned)e[0] | ((unsigned)e[1] << 16);
        o.y = (unsigned)e[2] | ((unsigned)e[3] << 16);
        o.z = (unsigned)e[4] | ((unsigned)e[5] << 16);
        o.w = (unsigned)e[6] | ((unsigned)e[7] << 16);
        *(uint4*)(W2s + (size_t)idx*8) = o;
    } else if (blk < 148) {
        int idx = (blk-76)*256 + tid;       // [0, 18432) = 8*36*64
        int n = idx & 63, q = idx >> 6;     // q = b*36 + p
        int p = q % 36, b = q / 36;
        int di = p/9, t = p%9;
        float s = 0.f;
        for (int j = 0; j < 64; ++j)
            s += c2f[b*64 + j] * pk[(di*128 + 64 + j)*9 + t] * W1[((1+di)*128 + 64 + j)*64 + n];
        V[(size_t)q*64 + n] = s;
    } else {
        for (int it = tid; it < 512; it += 256) {
            int b = it >> 6, n = it & 63;
            float s = b1[n];
            for (int j = 0; j < 64; ++j) s += c2f[b*64 + j]*W1[(64 + j)*64 + n];
            hcp[it] = s;
        }
    }
}

// ---------------- main fused kernel -----------------------------------------
#define HID_S 72

__global__ __launch_bounds__(256) void nca_main(
    const unsigned short* __restrict__ xp,
    const unsigned short* __restrict__ U,
    const unsigned short* __restrict__ W2s,
    const float* __restrict__ V,
    const float* __restrict__ hcp,
    const float* __restrict__ b2,
    float* __restrict__ out)
{
    // pool: U double-buffer [2][4 pos][4096 shorts] = 65536 B.
    // After the position loop it is reused as hid[256][HID_S] (36864 B).
    __shared__ unsigned short pool[32768];
    __shared__ float V_l[36*64];              // 9216 B
    __shared__ float Cx_l[16*64];             // 4096 B
    __shared__ float Cy_l[2*64];              //  512 B
    __shared__ float hc2_l[64];               //  256 B   -> total 79616 B (2 blocks/CU)

    const int tid = threadIdx.x;
    const int blk = blockIdx.x;
    const int b  = blk & 7;                   // XCD-local batch
    const int y0 = (blk >> 3) * 2;

    // ---- stage V + U chunk0 (pos 0..3) ----
    {
        const float4* Vg = (const float4*)(V + (size_t)b*2304);
        for (int i = tid; i < 576; i += 256) ((float4*)V_l)[i] = Vg[i];
        const uint4* Ug = (const uint4*)U;    // chunk0 = 2048 uint4
        uint4* dst = (uint4*)pool;
        #pragma unroll
        for (int i = 0; i < 8; ++i) dst[i*256 + tid] = Ug[i*256 + tid];
    }
    __syncthreads();
    for (int it = tid; it < 1024; it += 256) {      // Cx: x-edge correction
        int xi = it >> 6, n = it & 63;
        int xx = xi < 8 ? xi : 112 + xi;
        float s = 0.f;
        #pragma unroll
        for (int di = 0; di < 4; ++di) {
            int d = 1 << di;
            int dxo = (xx < d) ? 0 : ((xx >= 128 - d) ? 2 : -1);
            if (dxo >= 0) {
                s += V_l[(di*9 + 0*3 + dxo)*64 + n];
                s += V_l[(di*9 + 1*3 + dxo)*64 + n];
                s += V_l[(di*9 + 2*3 + dxo)*64 + n];
            }
        }
        Cx_l[it] = s;
    }
    for (int it = tid; it < 128; it += 256) {       // Cy for this block's 2 rows
        int r = it >> 6, n = it & 63;
        int yy = y0 + r;
        float s = 0.f;
        #pragma unroll
        for (int di = 0; di < 4; ++di) {
            int d = 1 << di;
            int dyo = (yy < d) ? 0 : ((yy >= 128 - d) ? 2 : -1);
            if (dyo >= 0) {
                s += V_l[(di*9 + dyo*3 + 0)*64 + n];
                s += V_l[(di*9 + dyo*3 + 1)*64 + n];
                s += V_l[(di*9 + dyo*3 + 2)*64 + n];
            }
        }
        Cy_l[it] = s;
    }
    if (tid < 64) {
        float s = hcp[b*64 + tid];
        for (int p = 0; p < 36; ++p) s += V_l[p*64 + tid];
        hc2_l[tid] = s;
    }
    __syncthreads();

    // ---- geometry ----
    const int lane = tid & 63;
    const int w    = tid >> 6;          // wave: row = y0 + (w>>1), x-half = (w&1)*64
    const int y    = y0 + (w >> 1);
    const int xw   = (w & 1) * 64;
    const int ln15 = lane & 15;
    const int oct  = lane >> 4;

    const unsigned short* base0 = xp + (size_t)b*XBATCH + (size_t)(oct >> 1)*XPLANE
                                + (size_t)(y + 8)*XROW + (size_t)(xw + ln15 + 8)*16
                                + (oct & 1)*8;

    f32x4 acc[4][4];
    #pragma unroll
    for (int mt = 0; mt < 4; ++mt)
        #pragma unroll
        for (int nt = 0; nt < 4; ++nt) {
            acc[mt][nt][0] = 0.f; acc[mt][nt][1] = 0.f;
            acc[mt][nt][2] = 0.f; acc[mt][nt][3] = 0.f;
        }

    static constexpr int OFF[37] = {
        0,
        (-1*144-1)*16, (-1*144)*16, (-1*144+1)*16,
        (-1)*16,       0*16,        (1)*16,
        ( 1*144-1)*16, ( 1*144)*16, ( 1*144+1)*16,
        (-2*144-2)*16, (-2*144)*16, (-2*144+2)*16,
        (-2)*16,       0*16,        (2)*16,
        ( 2*144-2)*16, ( 2*144)*16, ( 2*144+2)*16,
        (-4*144-4)*16, (-4*144)*16, (-4*144+4)*16,
        (-4)*16,       0*16,        (4)*16,
        ( 4*144-4)*16, ( 4*144)*16, ( 4*144+4)*16,
        (-8*144-8)*16, (-8*144)*16, (-8*144+8)*16,
        (-8)*16,       0*16,        (8)*16,
        ( 8*144-8)*16, ( 8*144)*16, ( 8*144+8)*16
    };

    // A register double-buffer
    s16x8 avc[2][4];
    #pragma unroll
    for (int kc2 = 0; kc2 < 2; ++kc2)
        #pragma unroll
        for (int mt = 0; mt < 4; ++mt)
            avc[kc2][mt] = *(const s16x8*)(base0 + OFF[0] + kc2*(2*XPLANE) + mt*256);

    // chunks 0..8 each hold 4 positions; position 36 rides as chunk 9 (buf1, slot 0)
    #pragma unroll 1
    for (int ci = 0; ci < 9; ++ci) {
        // issue global loads for next chunk (positions 4ci+4 .. ; ci=8 -> pos 36 only)
        const int nsw = (ci == 8) ? 2 : 8;
        uint4 st[8];
        {
            const uint4* src = (const uint4*)(U + (size_t)(ci + 1)*16384);
            #pragma unroll
            for (int i = 0; i < 8; ++i)
                if (i < nsw) st[i] = src[i*256 + tid];
        }
        unsigned short* Ul = pool + (ci & 1)*16384;
        #pragma unroll
        for (int j = 0; j < 4; ++j) {
            const int pos = ci*4 + j;
            // prefetch A for pos+1 (max 36)
            s16x8 avn[2][4];
            {
                const unsigned short* rp = base0 + OFF[pos + 1];
                #pragma unroll
                for (int kc2 = 0; kc2 < 2; ++kc2)
                    #pragma unroll
                    for (int mt = 0; mt < 4; ++mt)
                        avn[kc2][mt] = *(const s16x8*)(rp + kc2*(2*XPLANE) + mt*256);
            }
            const unsigned short* Up = Ul + j*4096 + lane*8;
            #pragma unroll
            for (int kc2 = 0; kc2 < 2; ++kc2) {
                #pragma unroll
                for (int nt = 0; nt < 4; ++nt) {
                    s16x8 bf = *(const s16x8*)(Up + kc2*2048 + nt*512);
                    #pragma unroll
                    for (int mt = 0; mt < 4; ++mt)
                        acc[mt][nt] = __builtin_amdgcn_mfma_f32_16x16x32_bf16(avc[kc2][mt], bf, acc[mt][nt], 0, 0, 0);
                }
            }
            #pragma unroll
            for (int kc2 = 0; kc2 < 2; ++kc2)
                #pragma unroll
                for (int mt = 0; mt < 4; ++mt)
                    avc[kc2][mt] = avn[kc2][mt];
        }
        // publish next chunk
        {
            uint4* dst = (uint4*)(pool + ((ci + 1) & 1)*16384);
            #pragma unroll
            for (int i = 0; i < 8; ++i)
                if (i < nsw) dst[i*256 + tid] = st[i];
        }
        __syncthreads();
    }
    // tail: position 36 from buf1 slot 0 (A already in avc)
    {
        const unsigned short* Up = pool + 16384 + lane*8;
        #pragma unroll
        for (int kc2 = 0; kc2 < 2; ++kc2) {
            #pragma unroll
            for (int nt = 0; nt < 4; ++nt) {
                s16x8 bf = *(const s16x8*)(Up + kc2*2048 + nt*512);
                #pragma unroll
                for (int mt = 0; mt < 4; ++mt)
                    acc[mt][nt] = __builtin_amdgcn_mfma_f32_16x16x32_bf16(avc[kc2][mt], bf, acc[mt][nt], 0, 0, 0);
            }
        }
    }
    __syncthreads();   // all waves done reading pool -> safe to reuse as hid

    // ---- epilogue 1: + hc2 - corrections, GELU, write hid (bf16) ----
    unsigned short* hid = pool;               // [256][HID_S] = 36864 B
    const bool yedge = (y < 8) || (y >= 120);
    #pragma unroll
    for (int mt = 0; mt < 4; ++mt) {
        #pragma unroll
        for (int nt = 0; nt < 4; ++nt) {
            const int n = nt*16 + ln15;
            const float hcv = hc2_l[n];
            const float cyv = yedge ? Cy_l[(w >> 1)*64 + n] : 0.f;
            #pragma unroll
            for (int r = 0; r < 4; ++r) {
                int m = oct*4 + r;                  // C row = (lane>>4)*4 + reg
                int x = xw + mt*16 + m;
                float h = acc[mt][nt][r] + hcv - cyv;
                if (x < 8 || x >= 120) {
                    int xi = (x < 8) ? x : (x - 112);
                    h -= Cx_l[xi*64 + n];
                    if (yedge) {                    // corner double-subtract fix
                        #pragma unroll
                        for (int di = 0; di < 4; ++di) {
                            int d = 1 << di;
                            int dyo = (y < d) ? 0 : ((y >= 128 - d) ? 2 : -1);
                            int dxo = (x < d) ? 0 : ((x >= 128 - d) ? 2 : -1);
                            if (dyo >= 0 && dxo >= 0)
                                h += V_l[(di*9 + dyo*3 + dxo)*64 + n];
                        }
                    }
                }
                float u = 0.7978845608028654f * (h + 0.044715f*h*h*h);
                float g = h / (1.f + __expf(-2.f*u));
                hid[(w*64 + mt*16 + m)*HID_S + n] = f2bf(g);
            }
        }
    }
    // each wave reads back only its own 64 hid rows -> no barrier needed

    // ---- GEMM2: y = hid @ W2 + b2 ----
    f32x4 acc2[4][4];
    #pragma unroll
    for (int mt = 0; mt < 4; ++mt)
        #pragma unroll
        for (int nt = 0; nt < 4; ++nt) {
            acc2[mt][nt][0] = 0.f; acc2[mt][nt][1] = 0.f;
            acc2[mt][nt][2] = 0.f; acc2[mt][nt][3] = 0.f;
        }
    #pragma unroll
    for (int kc2 = 0; kc2 < 2; ++kc2) {
        s16x8 a2[4];
        #pragma unroll
        for (int mt = 0; mt < 4; ++mt)
            a2[mt] = *(const s16x8*)&hid[(w*64 + mt*16 + ln15)*HID_S + kc2*32 + oct*8];
        #pragma unroll
        for (int nt = 0; nt < 4; ++nt) {
            s16x8 bf = *(const s16x8*)(W2s + ((size_t)(kc2*4 + nt)*64 + lane)*8);
            #pragma unroll
            for (int mt = 0; mt < 4; ++mt)
                acc2[mt][nt] = __builtin_amdgcn_mfma_f32_16x16x32_bf16(a2[mt], bf, acc2[mt][nt], 0, 0, 0);
        }
    }

    float* ob = out + ((size_t)(b*128 + y))*128*64;
    #pragma unroll
    for (int nt = 0; nt < 4; ++nt) {
        const float b2v = b2[nt*16 + ln15];
        #pragma unroll
        for (int mt = 0; mt < 4; ++mt) {
            #pragma unroll
            for (int r = 0; r < 4; ++r) {
                int x = xw + mt*16 + oct*4 + r;
                ob[(size_t)x*64 + nt*16 + ln15] = acc2[mt][nt][r] + b2v;
            }
        }
    }
}

// ---------------- launch ----------------------------------------------------
extern "C" void kernel_launch(void* const* d_in, const int* in_sizes, int n_in,
                              void* d_out, int out_size, void* d_ws, size_t ws_size,
                              hipStream_t stream) {
    const float* x   = (const float*)d_in[0];
    const float* c   = (const float*)d_in[1];
    // d_in[2..5] = Wq,bq,Wk,bk : unused (softmax weights sum to 1 -> pool == v)
    const float* Wv  = (const float*)d_in[6];
    const float* bv  = (const float*)d_in[7];
    const float* Wo  = (const float*)d_in[8];
    const float* bo  = (const float*)d_in[9];
    const float* lng = (const float*)d_in[10];
    const float* lnb = (const float*)d_in[11];
    const float* pk  = (const float*)d_in[12];
    const float* W1  = (const float*)d_in[13];
    const float* b1  = (const float*)d_in[14];
    const float* W2  = (const float*)d_in[15];
    const float* b2  = (const float*)d_in[16];
    float* out = (float*)d_out;

    char* w = (char*)d_ws;
    unsigned short* xpb = (unsigned short*)(w);                  // 21,233,664 B
    unsigned short* Uf  = (unsigned short*)(w + 21233664);       //    303,104 B (37*512 frags; padded reads to 327,680 OK)
    unsigned short* W2s = (unsigned short*)(w + 21561344);       //      8,192 B
    float*          V   = (float*)         (w + 21569536);       //     73,728 B
    float*          hcp = (float*)         (w + 21643264);       //      2,048 B
    float*          c2f = (float*)         (w + 21645312);       //      2,048 B (end 21,647,360)

    prepA<<<1064, 256, 0, stream>>>(x, c, Wv, bv, Wo, bo, lng, lnb, xpb, c2f, out + 8388608);
    prepB<<<149, 256, 0, stream>>>(pk, W1, W2, b1, c2f, Uf, W2s, V, hcp);
    nca_main<<<512, 256, 0, stream>>>(xpb, Uf, W2s, V, hcp, b2, out);
}

// Round 6
// 171.616 us; speedup vs baseline: 1.1744x; 1.1744x over previous
//
#include <hip/hip_runtime.h>
#include <hip/hip_bf16.h>
#include <math.h>

// B=8, H=W=128, CH=64, OC=64, NCA_C=128, K=3, dils {1,2,4,8}, HID=64
// out: y [8,128,128,64] fp32 (8388608) then c2 [8,64] fp32 (512)
//
// Depthwise conv folded into GEMM1: hidden[p] = sum_{37 pos} xpad[p+delta,0:64] @ U_pos.
// Round-6: B (U) staged to LDS via __builtin_amdgcn_global_load_lds (width 16, async DMA,
// zero VGPR footprint -- round 5's register-staged copy spilled to scratch: WRITE_SIZE
// 33->167 MB). A register-double-buffered from zero-padded bf16 image (round-4 proven).
// b = blk&7 -> XCD-local L2 (FETCH ~12 MB verified).

typedef float  f32x4 __attribute__((ext_vector_type(4)));
typedef short  s16x8 __attribute__((ext_vector_type(8)));

static __device__ __forceinline__ unsigned short f2bf(float f) {
    __hip_bfloat16 h = __float2bfloat16(f);
    unsigned short u; __builtin_memcpy(&u, &h, 2); return u;
}

// xpad layout: [b][plane(4)][yy(144)][xx(144)][16ch] bf16
#define XROW   2304
#define XPLANE 331776
#define XBATCH 1327104

// ---------------- prepA: x -> padded bf16, pad zero-fill, c2 ----------------
__global__ void prepA(const float* __restrict__ x, const float* __restrict__ c,
                      const float* __restrict__ Wv, const float* __restrict__ bv,
                      const float* __restrict__ Wo, const float* __restrict__ bo,
                      const float* __restrict__ lng, const float* __restrict__ lnb,
                      unsigned short* __restrict__ xp, float* __restrict__ c2f,
                      float* __restrict__ outc2)
{
    const int blk = blockIdx.x, tid = threadIdx.x;
    if (blk < 512) {
        int i = blk*256 + tid;               // px index [0,131072)
        int xc = i & 127, y = (i >> 7) & 127, b = i >> 14;
        const float* src = x + (size_t)i*64;
        unsigned short* dstb = xp + ((size_t)b*4*144 + (y+8))*XROW + (xc+8)*16;
        #pragma unroll
        for (int p = 0; p < 4; ++p) {
            float4 f0 = *(const float4*)(src + p*16 + 0);
            float4 f1 = *(const float4*)(src + p*16 + 4);
            float4 f2 = *(const float4*)(src + p*16 + 8);
            float4 f3 = *(const float4*)(src + p*16 + 12);
            uint4 o0, o1;
            o0.x = (unsigned)f2bf(f0.x) | ((unsigned)f2bf(f0.y) << 16);
            o0.y = (unsigned)f2bf(f0.z) | ((unsigned)f2bf(f0.w) << 16);
            o0.z = (unsigned)f2bf(f1.x) | ((unsigned)f2bf(f1.y) << 16);
            o0.w = (unsigned)f2bf(f1.z) | ((unsigned)f2bf(f1.w) << 16);
            o1.x = (unsigned)f2bf(f2.x) | ((unsigned)f2bf(f2.y) << 16);
            o1.y = (unsigned)f2bf(f2.z) | ((unsigned)f2bf(f2.w) << 16);
            o1.z = (unsigned)f2bf(f3.x) | ((unsigned)f2bf(f3.y) << 16);
            o1.w = (unsigned)f2bf(f3.z) | ((unsigned)f2bf(f3.w) << 16);
            unsigned short* d = dstb + (size_t)p*XPLANE;
            *(uint4*)d = o0; *(uint4*)(d + 8) = o1;
        }
    } else if (blk < 1056) {
        int idx = (blk - 512)*256 + tid;     // [0,139264) pad px
        int bp = idx / 4352;                 // b*4+plane
        int r  = idx - bp*4352;
        int yy, xx;
        if (r < 2304) { int ry = r / 144; xx = r - ry*144; yy = (ry < 8) ? ry : 128 + ry; }
        else { int r2 = r - 2304; yy = 8 + (r2 >> 4); int xi = r2 & 15; xx = (xi < 8) ? xi : 128 + xi; }
        uint4 z = make_uint4(0,0,0,0);
        unsigned short* d = xp + ((size_t)bp*144 + yy)*XROW + xx*16;
        *(uint4*)d = z; *(uint4*)(d + 8) = z;
    } else {
        // c2 = c + LN(v@Wo + bo + c), v = c@Wv + bv  (softmax pool == v exactly)
        const int b = blk - 1056;
        __shared__ float sc[64], sv[64];
        const int j = tid;
        if (j < 64) sc[j] = c[b*64 + j];
        __syncthreads();
        if (j < 64) {
            float v = bv[j];
            for (int i = 0; i < 64; ++i) v += sc[i]*Wv[i*64 + j];
            sv[j] = v;
        }
        __syncthreads();
        if (j < 64) {
            float t = bo[j] + sc[j];
            for (int i = 0; i < 64; ++i) t += sv[i]*Wo[i*64 + j];
            float s = t;
            for (int o = 32; o > 0; o >>= 1) s += __shfl_xor(s, o);
            float m = s * (1.f/64.f);
            float dq = (t - m)*(t - m);
            for (int o = 32; o > 0; o >>= 1) dq += __shfl_xor(dq, o);
            float a = (t - m) / sqrtf(dq*(1.f/64.f) + 1e-5f) * lng[j] + lnb[j];
            float c2 = sc[j] + a;
            c2f[b*64 + j] = c2;
            outc2[b*64 + j] = c2;
        }
    }
}

// ---------------- prepB: U frags, W2 frags, V vectors, hcpart ---------------
__global__ void prepB(const float* __restrict__ pk, const float* __restrict__ W1,
                      const float* __restrict__ W2, const float* __restrict__ b1,
                      const float* __restrict__ c2f,
                      unsigned short* __restrict__ Uf, unsigned short* __restrict__ W2s,
                      float* __restrict__ V, float* __restrict__ hcp)
{
    const int blk = blockIdx.x, tid = threadIdx.x;
    if (blk < 74) {
        int idx = blk*256 + tid;            // [0, 18944) = 37*512
        int lane = idx & 63, nt = (idx >> 6) & 3, kc2 = (idx >> 8) & 1, pos = idx >> 9;
        int n  = nt*16 + (lane & 15);
        int k0 = kc2*32 + (lane >> 4)*8;
        unsigned short e[8];
        if (pos == 0) {
            #pragma unroll
            for (int j = 0; j < 8; ++j) e[j] = f2bf(W1[(k0+j)*64 + n]);
        } else {
            int di = (pos-1)/9, t = (pos-1)%9;
            #pragma unroll
            for (int j = 0; j < 8; ++j) {
                int ch = k0 + j;
                e[j] = f2bf(pk[(di*128 + ch)*9 + t] * W1[((1+di)*128 + ch)*64 + n]);
            }
        }
        uint4 o;
        o.x = (unsigned)e[0] | ((unsigned)e[1] << 16);
        o.y = (unsigned)e[2] | ((unsigned)e[3] << 16);
        o.z = (unsigned)e[4] | ((unsigned)e[5] << 16);
        o.w = (unsigned)e[6] | ((unsigned)e[7] << 16);
        *(uint4*)(Uf + (size_t)idx*8) = o;
    } else if (blk < 76) {
        int idx = (blk-74)*256 + tid;       // [0,512)
        int lane = idx & 63, nt = (idx >> 6) & 3, kc2 = (idx >> 8) & 1;
        int n  = nt*16 + (lane & 15);
        int k0 = kc2*32 + (lane >> 4)*8;
        unsigned short e[8];
        #pragma unroll
        for (int j = 0; j < 8; ++j) e[j] = f2bf(W2[(k0+j)*64 + n]);
        uint4 o;
        o.x = (unsigned)e[0] | ((unsigned)e[1] << 16);
        o.y = (unsigned)e[2] | ((unsigned)e[3] << 16);
        o.z = (unsigned)e[4] | ((unsigned)e[5] << 16);
        o.w = (unsigned)e[6] | ((unsigned)e[7] << 16);
        *(uint4*)(W2s + (size_t)idx*8) = o;
    } else if (blk < 148) {
        int idx = (blk-76)*256 + tid;       // [0, 18432) = 8*36*64
        int n = idx & 63, q = idx >> 6;     // q = b*36 + p
        int p = q % 36, b = q / 36;
        int di = p/9, t = p%9;
        float s = 0.f;
        for (int j = 0; j < 64; ++j)
            s += c2f[b*64 + j] * pk[(di*128 + 64 + j)*9 + t] * W1[((1+di)*128 + 64 + j)*64 + n];
        V[(size_t)q*64 + n] = s;
    } else {
        for (int it = tid; it < 512; it += 256) {
            int b = it >> 6, n = it & 63;
            float s = b1[n];
            for (int j = 0; j < 64; ++j) s += c2f[b*64 + j]*W1[(64 + j)*64 + n];
            hcp[it] = s;
        }
    }
}

// ---------------- main fused kernel -----------------------------------------
#define HID_S 72

__global__ __launch_bounds__(256) void nca_main(
    const unsigned short* __restrict__ xp,
    const unsigned short* __restrict__ U,
    const unsigned short* __restrict__ W2s,
    const float* __restrict__ V,
    const float* __restrict__ hcp,
    const float* __restrict__ b2,
    float* __restrict__ out)
{
    // pool: U double-buffer [2][4 pos][4096 shorts] = 65536 B.
    // After the position loop it is reused as hid[256][HID_S] (36864 B).
    __shared__ unsigned short pool[32768];
    __shared__ float V_l[36*64];              // 9216 B
    __shared__ float Cx_l[16*64];             // 4096 B
    __shared__ float Cy_l[2*64];              //  512 B
    __shared__ float hc2_l[64];               //  256 B   -> total 79616 B (2 blocks/CU)

    const int tid = threadIdx.x;
    const int blk = blockIdx.x;
    const int b  = blk & 7;                   // XCD-local batch
    const int y0 = (blk >> 3) * 2;

    const int lane = tid & 63;
    const int w    = tid >> 6;

    // async DMA stage of U chunk `ci` (4 positions = 32768 B; tail chunk 9 = 8192 B)
    // into pool buf (ci&1). Wave w copies its contiguous segment in 1024 B calls.
    auto stage = [&](int ci) {
        const int nb  = (ci == 9) ? 8192 : 32768;       // bytes
        const int pw  = nb >> 2;                         // bytes per wave
        const unsigned short* src = U + (size_t)ci*16384 + (size_t)w*(pw >> 1) + lane*8;
        unsigned short* dst = pool + (ci & 1)*16384 + w*(pw >> 1);
        #pragma unroll
        for (int i = 0; i < 8; ++i) {
            if (i*1024 < pw) {
                __builtin_amdgcn_global_load_lds(
                    (const __attribute__((address_space(1))) unsigned int*)(src + i*512),
                    (__attribute__((address_space(3))) unsigned int*)(dst + i*512),
                    16, 0, 0);
            }
        }
    };

    // ---- stage V + U chunk0 ----
    stage(0);
    {
        const float4* Vg = (const float4*)(V + (size_t)b*2304);
        for (int i = tid; i < 576; i += 256) ((float4*)V_l)[i] = Vg[i];
    }
    __syncthreads();
    for (int it = tid; it < 1024; it += 256) {      // Cx: x-edge correction
        int xi = it >> 6, n = it & 63;
        int xx = xi < 8 ? xi : 112 + xi;
        float s = 0.f;
        #pragma unroll
        for (int di = 0; di < 4; ++di) {
            int d = 1 << di;
            int dxo = (xx < d) ? 0 : ((xx >= 128 - d) ? 2 : -1);
            if (dxo >= 0) {
                s += V_l[(di*9 + 0*3 + dxo)*64 + n];
                s += V_l[(di*9 + 1*3 + dxo)*64 + n];
                s += V_l[(di*9 + 2*3 + dxo)*64 + n];
            }
        }
        Cx_l[it] = s;
    }
    for (int it = tid; it < 128; it += 256) {       // Cy for this block's 2 rows
        int r = it >> 6, n = it & 63;
        int yy = y0 + r;
        float s = 0.f;
        #pragma unroll
        for (int di = 0; di < 4; ++di) {
            int d = 1 << di;
            int dyo = (yy < d) ? 0 : ((yy >= 128 - d) ? 2 : -1);
            if (dyo >= 0) {
                s += V_l[(di*9 + dyo*3 + 0)*64 + n];
                s += V_l[(di*9 + dyo*3 + 1)*64 + n];
                s += V_l[(di*9 + dyo*3 + 2)*64 + n];
            }
        }
        Cy_l[it] = s;
    }
    if (tid < 64) {
        float s = hcp[b*64 + tid];
        for (int p = 0; p < 36; ++p) s += V_l[p*64 + tid];
        hc2_l[tid] = s;
    }

    // ---- geometry ----
    const int y    = y0 + (w >> 1);
    const int xw   = (w & 1) * 64;
    const int ln15 = lane & 15;
    const int oct  = lane >> 4;

    const unsigned short* base0 = xp + (size_t)b*XBATCH + (size_t)(oct >> 1)*XPLANE
                                + (size_t)(y + 8)*XROW + (size_t)(xw + ln15 + 8)*16
                                + (oct & 1)*8;

    f32x4 acc[4][4];
    #pragma unroll
    for (int mt = 0; mt < 4; ++mt)
        #pragma unroll
        for (int nt = 0; nt < 4; ++nt) {
            acc[mt][nt][0] = 0.f; acc[mt][nt][1] = 0.f;
            acc[mt][nt][2] = 0.f; acc[mt][nt][3] = 0.f;
        }

    static constexpr int OFF[37] = {
        0,
        (-1*144-1)*16, (-1*144)*16, (-1*144+1)*16,
        (-1)*16,       0*16,        (1)*16,
        ( 1*144-1)*16, ( 1*144)*16, ( 1*144+1)*16,
        (-2*144-2)*16, (-2*144)*16, (-2*144+2)*16,
        (-2)*16,       0*16,        (2)*16,
        ( 2*144-2)*16, ( 2*144)*16, ( 2*144+2)*16,
        (-4*144-4)*16, (-4*144)*16, (-4*144+4)*16,
        (-4)*16,       0*16,        (4)*16,
        ( 4*144-4)*16, ( 4*144)*16, ( 4*144+4)*16,
        (-8*144-8)*16, (-8*144)*16, (-8*144+8)*16,
        (-8)*16,       0*16,        (8)*16,
        ( 8*144-8)*16, ( 8*144)*16, ( 8*144+8)*16
    };

    // A register double-buffer
    s16x8 avc[2][4];
    #pragma unroll
    for (int kc2 = 0; kc2 < 2; ++kc2)
        #pragma unroll
        for (int mt = 0; mt < 4; ++mt)
            avc[kc2][mt] = *(const s16x8*)(base0 + OFF[0] + kc2*(2*XPLANE) + mt*256);

    __syncthreads();   // chunk0 DMA drained (vmcnt) + tables published

    // chunks 0..8 hold pos 0..35; chunk 9 = pos 36 (staged during ci=8)
    #pragma unroll 1
    for (int ci = 0; ci < 9; ++ci) {
        stage(ci + 1);                           // async DMA into other buffer
        const unsigned short* Ul = pool + (ci & 1)*16384;
        #pragma unroll
        for (int j = 0; j < 4; ++j) {
            const int pos = ci*4 + j;
            s16x8 avn[2][4];                     // A prefetch for pos+1 (max 36)
            {
                const unsigned short* rp = base0 + OFF[pos + 1];
                #pragma unroll
                for (int kc2 = 0; kc2 < 2; ++kc2)
                    #pragma unroll
                    for (int mt = 0; mt < 4; ++mt)
                        avn[kc2][mt] = *(const s16x8*)(rp + kc2*(2*XPLANE) + mt*256);
            }
            const unsigned short* Up = Ul + j*4096 + lane*8;
            #pragma unroll
            for (int kc2 = 0; kc2 < 2; ++kc2) {
                #pragma unroll
                for (int nt = 0; nt < 4; ++nt) {
                    s16x8 bf = *(const s16x8*)(Up + kc2*2048 + nt*512);
                    #pragma unroll
                    for (int mt = 0; mt < 4; ++mt)
                        acc[mt][nt] = __builtin_amdgcn_mfma_f32_16x16x32_bf16(avc[kc2][mt], bf, acc[mt][nt], 0, 0, 0);
                }
            }
            #pragma unroll
            for (int kc2 = 0; kc2 < 2; ++kc2)
                #pragma unroll
                for (int mt = 0; mt < 4; ++mt)
                    avc[kc2][mt] = avn[kc2][mt];
        }
        __syncthreads();   // drains DMA (vmcnt0) + publishes next buffer
    }
    // tail: position 36 from buf1 slot 0 (A already in avc)
    {
        const unsigned short* Up = pool + 16384 + lane*8;
        #pragma unroll
        for (int kc2 = 0; kc2 < 2; ++kc2) {
            #pragma unroll
            for (int nt = 0; nt < 4; ++nt) {
                s16x8 bf = *(const s16x8*)(Up + kc2*2048 + nt*512);
                #pragma unroll
                for (int mt = 0; mt < 4; ++mt)
                    acc[mt][nt] = __builtin_amdgcn_mfma_f32_16x16x32_bf16(avc[kc2][mt], bf, acc[mt][nt], 0, 0, 0);
            }
        }
    }
    __syncthreads();   // all waves done reading pool -> safe to reuse as hid

    // ---- epilogue 1: + hc2 - corrections, GELU, write hid (bf16) ----
    unsigned short* hid = pool;               // [256][HID_S] = 36864 B
    const bool yedge = (y < 8) || (y >= 120);
    #pragma unroll
    for (int mt = 0; mt < 4; ++mt) {
        #pragma unroll
        for (int nt = 0; nt < 4; ++nt) {
            const int n = nt*16 + ln15;
            const float hcv = hc2_l[n];
            const float cyv = yedge ? Cy_l[(w >> 1)*64 + n] : 0.f;
            #pragma unroll
            for (int r = 0; r < 4; ++r) {
                int m = oct*4 + r;                  // C row = (lane>>4)*4 + reg
                int x = xw + mt*16 + m;
                float h = acc[mt][nt][r] + hcv - cyv;
                if (x < 8 || x >= 120) {
                    int xi = (x < 8) ? x : (x - 112);
                    h -= Cx_l[xi*64 + n];
                    if (yedge) {                    // corner double-subtract fix
                        #pragma unroll
                        for (int di = 0; di < 4; ++di) {
                            int d = 1 << di;
                            int dyo = (y < d) ? 0 : ((y >= 128 - d) ? 2 : -1);
                            int dxo = (x < d) ? 0 : ((x >= 128 - d) ? 2 : -1);
                            if (dyo >= 0 && dxo >= 0)
                                h += V_l[(di*9 + dyo*3 + dxo)*64 + n];
                        }
                    }
                }
                float u = 0.7978845608028654f * (h + 0.044715f*h*h*h);
                float g = h / (1.f + __expf(-2.f*u));
                hid[(w*64 + mt*16 + m)*HID_S + n] = f2bf(g);
            }
        }
    }
    // each wave reads back only its own 64 hid rows -> no barrier needed

    // ---- GEMM2: y = hid @ W2 + b2 ----
    f32x4 acc2[4][4];
    #pragma unroll
    for (int mt = 0; mt < 4; ++mt)
        #pragma unroll
        for (int nt = 0; nt < 4; ++nt) {
            acc2[mt][nt][0] = 0.f; acc2[mt][nt][1] = 0.f;
            acc2[mt][nt][2] = 0.f; acc2[mt][nt][3] = 0.f;
        }
    #pragma unroll
    for (int kc2 = 0; kc2 < 2; ++kc2) {
        s16x8 a2[4];
        #pragma unroll
        for (int mt = 0; mt < 4; ++mt)
            a2[mt] = *(const s16x8*)&hid[(w*64 + mt*16 + ln15)*HID_S + kc2*32 + oct*8];
        #pragma unroll
        for (int nt = 0; nt < 4; ++nt) {
            s16x8 bf = *(const s16x8*)(W2s + ((size_t)(kc2*4 + nt)*64 + lane)*8);
            #pragma unroll
            for (int mt = 0; mt < 4; ++mt)
                acc2[mt][nt] = __builtin_amdgcn_mfma_f32_16x16x32_bf16(a2[mt], bf, acc2[mt][nt], 0, 0, 0);
        }
    }

    float* ob = out + ((size_t)(b*128 + y))*128*64;
    #pragma unroll
    for (int nt = 0; nt < 4; ++nt) {
        const float b2v = b2[nt*16 + ln15];
        #pragma unroll
        for (int mt = 0; mt < 4; ++mt) {
            #pragma unroll
            for (int r = 0; r < 4; ++r) {
                int x = xw + mt*16 + oct*4 + r;
                ob[(size_t)x*64 + nt*16 + ln15] = acc2[mt][nt][r] + b2v;
            }
        }
    }
}

// ---------------- launch ----------------------------------------------------
extern "C" void kernel_launch(void* const* d_in, const int* in_sizes, int n_in,
                              void* d_out, int out_size, void* d_ws, size_t ws_size,
                              hipStream_t stream) {
    const float* x   = (const float*)d_in[0];
    const float* c   = (const float*)d_in[1];
    // d_in[2..5] = Wq,bq,Wk,bk : unused (softmax weights sum to 1 -> pool == v)
    const float* Wv  = (const float*)d_in[6];
    const float* bv  = (const float*)d_in[7];
    const float* Wo  = (const float*)d_in[8];
    const float* bo  = (const float*)d_in[9];
    const float* lng = (const float*)d_in[10];
    const float* lnb = (const float*)d_in[11];
    const float* pk  = (const float*)d_in[12];
    const float* W1  = (const float*)d_in[13];
    const float* b1  = (const float*)d_in[14];
    const float* W2  = (const float*)d_in[15];
    const float* b2  = (const float*)d_in[16];
    float* out = (float*)d_out;

    char* w = (char*)d_ws;
    unsigned short* xpb = (unsigned short*)(w);                  // 21,233,664 B
    unsigned short* Uf  = (unsigned short*)(w + 21233664);       //    303,104 B
    unsigned short* W2s = (unsigned short*)(w + 21561344);       //      8,192 B
    float*          V   = (float*)         (w + 21569536);       //     73,728 B
    float*          hcp = (float*)         (w + 21643264);       //      2,048 B
    float*          c2f = (float*)         (w + 21645312);       //      2,048 B (end 21,647,360)

    prepA<<<1064, 256, 0, stream>>>(x, c, Wv, bv, Wo, bo, lng, lnb, xpb, c2f, out + 8388608);
    prepB<<<149, 256, 0, stream>>>(pk, W1, W2, b1, c2f, Uf, W2s, V, hcp);
    nca_main<<<512, 256, 0, stream>>>(xpb, Uf, W2s, V, hcp, b2, out);
}